// Round 10
// baseline (264.581 us; speedup 1.0000x reference)
//
#include <hip/hip_runtime.h>
#include <hip/hip_bf16.h>

#define B_SZ  4096
#define IN_F  512
#define OUT_F 512
#define NC    64
#define PAIRS 32768               // OUT_F * NC
#define TOT   (IN_F * PAIRS)      // 16.8M
#define KTOT  (IN_F + NC)         // 576: combined GEMM K
#define RCH   32                  // k1 row-chunks (16 rows each)

typedef __attribute__((ext_vector_type(8))) short bf16x8;
typedef __attribute__((ext_vector_type(4))) float f32x4;

static __device__ inline unsigned short f2bf(float f) {
    __hip_bfloat16 h = __float2bfloat16(f);   // RNE
    return *(unsigned short*)&h;
}

// ---------------------------------------------------------------------------
// K1: R8 config with ONE change: plain loads instead of nontemporal.
// R8 counters: 42.5us, FETCH 98MB of 192MB compulsory -> ~94MB L3-served.
// Theory: nt marks lines no-retention, evicting half the (L3-sized, 192MB)
// input set between dispatches. Plain loads -> full L3 residency -> FETCH
// drops, k1 approaches L3 service rate. Single-variable test; revert if
// FETCH/dur regress.
// ---------------------------------------------------------------------------
__global__ __launch_bounds__(512)
void k1_partial(const float* __restrict__ cm,
                const float* __restrict__ clv,
                const float* __restrict__ eps,
                float* __restrict__ part,
                float* __restrict__ klpart,
                int S) {
    int pb = blockIdx.x & 15;            // pair-slice: 2048 pairs (8 KB/row)
    int rc = blockIdx.x >> 4;            // row-chunk: rows rc*16..+16
    int p4 = pb * 2048 + (threadIdx.x << 2);
    float Sf = (float)S;

    f32x4 s = {0.f, 0.f, 0.f, 0.f};
    float klp = 0.f;

    for (int g = 0; g < 2; ++g) {
        size_t base = (size_t)(rc * 16 + g * 8) * PAIRS + p4;
        f32x4 M[8], LV[8], ES[8];
#pragma unroll
        for (int ii = 0; ii < 8; ++ii)
            M[ii] = *(const f32x4*)(cm + base + (size_t)ii * PAIRS);
#pragma unroll
        for (int ii = 0; ii < 8; ++ii)
            LV[ii] = *(const f32x4*)(clv + base + (size_t)ii * PAIRS);
#pragma unroll
        for (int ii = 0; ii < 8; ++ii)
            ES[ii] = *(const f32x4*)(eps + base + (size_t)ii * PAIRS);
        for (int si = 1; si < S; ++si)   // dead for S==1
#pragma unroll
            for (int ii = 0; ii < 8; ++ii) {
                f32x4 e = *(const f32x4*)(eps + (size_t)si * TOT + base + (size_t)ii * PAIRS);
                ES[ii] += e;
            }

#pragma unroll
        for (int ii = 0; ii < 8; ++ii) {
            float e1x = __expf(0.5f * LV[ii].x);
            float e1y = __expf(0.5f * LV[ii].y);
            float e1z = __expf(0.5f * LV[ii].z);
            float e1w = __expf(0.5f * LV[ii].w);
            s.x += Sf * M[ii].x + ES[ii].x * e1x;
            s.y += Sf * M[ii].y + ES[ii].y * e1y;
            s.z += Sf * M[ii].z + ES[ii].z * e1z;
            s.w += Sf * M[ii].w + ES[ii].w * e1w;
            klp += (e1x*e1x + M[ii].x*M[ii].x - 1.f - LV[ii].x);
            klp += (e1y*e1y + M[ii].y*M[ii].y - 1.f - LV[ii].y);
            klp += (e1z*e1z + M[ii].z*M[ii].z - 1.f - LV[ii].z);
            klp += (e1w*e1w + M[ii].w*M[ii].w - 1.f - LV[ii].w);
        }
    }

    *(f32x4*)(part + (size_t)rc * PAIRS + p4) = s;

    for (int off = 32; off; off >>= 1)
        klp += __shfl_down(klp, off, 64);
    __shared__ float wsum[8];
    if ((threadIdx.x & 63) == 0) wsum[threadIdx.x >> 6] = klp;
    __syncthreads();
    if (threadIdx.x == 0) {
        float t = 0.f;
#pragma unroll
        for (int i = 0; i < 8; ++i) t += wsum[i];
        klpart[blockIdx.x] = t;
    }
}

// ---------------------------------------------------------------------------
// K_mid v3 (UNCHANGED from R8 — verified, part of the 225.8us config):
//   0..63   rbf via MFMA (dist^2 = ||x||^2 + ||c||^2 - 2 x.c) + xbf emit
//   64..127 csum reduce -> wct[*,512..575]
//   128..191 W^T -> wct cols 0..511
//   192     kl final
// ---------------------------------------------------------------------------
__global__ __launch_bounds__(512)
void k_mid3(const float* __restrict__ x,
            const float* __restrict__ centers,
            const float* __restrict__ log_sigma,
            const float* __restrict__ part,
            const float* __restrict__ klpart,
            const float* __restrict__ bw,
            unsigned short* __restrict__ rbf,
            unsigned short* __restrict__ wct,
            unsigned short* __restrict__ xbf,
            float* __restrict__ kl_out,
            float inv_S) {
    __shared__ __align__(16) float shbuf[5312];   // 21.25 KB, aliased per role
    int bid = blockIdx.x, t = threadIdx.x;

    if (bid < 64) {
        // =================== rbf-MFMA: rows b0..b0+63, all 64 centers ========
        unsigned short* As = (unsigned short*)shbuf;           // [64][72] bf16
        unsigned short* Cs = (unsigned short*)(shbuf + 2304);  // [64][72] bf16
        float* scr = shbuf + 4608;   // [512] partial scratch (cn, then xn)
        float* cn  = shbuf + 5120;   // [64] ||c||^2
        float* inv = shbuf + 5184;   // [64] 1/(2 sg^2 + 1e-8)
        float* xnf = shbuf + 5248;   // [64] ||x||^2

        int b0 = bid * 64;

        // ---- center norms + inv (f32 exact) ----
        {
            int n = t & 63, p = t >> 6;
            const float* cp = centers + (size_t)n * IN_F + p * 64;
            float s0 = 0.f, s1 = 0.f, s2 = 0.f, s3 = 0.f;
#pragma unroll
            for (int j = 0; j < 64; j += 4) {
                float4 v = *(const float4*)(cp + j);
                s0 = fmaf(v.x, v.x, s0); s1 = fmaf(v.y, v.y, s1);
                s2 = fmaf(v.z, v.z, s2); s3 = fmaf(v.w, v.w, s3);
            }
            scr[p * 64 + n] = (s0 + s1) + (s2 + s3);
        }
        __syncthreads();
        if (t < 64) {
            float s = 0.f;
#pragma unroll
            for (int p = 0; p < 8; ++p) s += scr[p * 64 + t];
            cn[t] = s;
            float sg = __expf(log_sigma[t]);
            inv[t] = 1.f / (2.f * sg * sg + 1e-8f);
        }
        __syncthreads();

        // ---- main loop: stage x/c tiles (f32->bf16), MFMA xc, emit xbf ----
        int ar = t >> 3, ah = t & 7;             // staging: row, k-octant(8)
        int lane = t & 63, wv = t >> 6;          // wv 0..7; MFMA on wv<4
        int fm = lane & 15, kg = lane >> 4;
        float xacc = 0.f;
        f32x4 acc[4] = {{0,0,0,0},{0,0,0,0},{0,0,0,0},{0,0,0,0}};

        for (int it = 0; it < 8; ++it) {
            int k0 = it * 64;
            const float* xp = x + (size_t)(b0 + ar) * IN_F + k0 + ah * 8;
            f32x4 v0 = *(const f32x4*)(xp);
            f32x4 v1 = *(const f32x4*)(xp + 4);
            const float* cp = centers + (size_t)ar * IN_F + k0 + ah * 8;
            f32x4 c0 = *(const f32x4*)(cp);
            f32x4 c1 = *(const f32x4*)(cp + 4);
            bf16x8 xb, cb;
            xb[0] = (short)f2bf(v0.x); xb[1] = (short)f2bf(v0.y);
            xb[2] = (short)f2bf(v0.z); xb[3] = (short)f2bf(v0.w);
            xb[4] = (short)f2bf(v1.x); xb[5] = (short)f2bf(v1.y);
            xb[6] = (short)f2bf(v1.z); xb[7] = (short)f2bf(v1.w);
            cb[0] = (short)f2bf(c0.x); cb[1] = (short)f2bf(c0.y);
            cb[2] = (short)f2bf(c0.z); cb[3] = (short)f2bf(c0.w);
            cb[4] = (short)f2bf(c1.x); cb[5] = (short)f2bf(c1.y);
            cb[6] = (short)f2bf(c1.z); cb[7] = (short)f2bf(c1.w);
            xacc += v0.x*v0.x + v0.y*v0.y + v0.z*v0.z + v0.w*v0.w
                  + v1.x*v1.x + v1.y*v1.y + v1.z*v1.z + v1.w*v1.w;
            __syncthreads();                       // prev MFMA done reading LDS
            *(bf16x8*)&As[ar * 72 + ah * 8] = xb;
            *(bf16x8*)&Cs[ar * 72 + ah * 8] = cb;
            *(bf16x8*)(xbf + (size_t)(b0 + ar) * IN_F + k0 + ah * 8) = xb;
            __syncthreads();
            if (wv < 4) {
                bf16x8 af0 = *(bf16x8*)&As[(wv * 16 + fm) * 72 + kg * 8];
                bf16x8 af1 = *(bf16x8*)&As[(wv * 16 + fm) * 72 + 32 + kg * 8];
#pragma unroll
                for (int nf = 0; nf < 4; ++nf) {
                    bf16x8 b0f = *(bf16x8*)&Cs[(nf * 16 + fm) * 72 + kg * 8];
                    acc[nf] = __builtin_amdgcn_mfma_f32_16x16x32_bf16(af0, b0f, acc[nf], 0, 0, 0);
                    bf16x8 b1f = *(bf16x8*)&Cs[(nf * 16 + fm) * 72 + 32 + kg * 8];
                    acc[nf] = __builtin_amdgcn_mfma_f32_16x16x32_bf16(af1, b1f, acc[nf], 0, 0, 0);
                }
            }
        }

        // ---- x row norms: reduce per-thread partials ----
        scr[ar * 8 + ah] = xacc;                   // scr last read pre-loop; safe
        __syncthreads();
        if (t < 64) {
            float s = 0.f;
#pragma unroll
            for (int p = 0; p < 8; ++p) s += scr[t * 8 + p];
            xnf[t] = s;
        }
        __syncthreads();

        // ---- epilogue: rbf = exp(-(xn + cn - 2 xc) * inv), C/D layout ----
        if (wv < 4) {
#pragma unroll
            for (int nf = 0; nf < 4; ++nf) {
                int c = nf * 16 + fm;
                float cnc = cn[c], ivc = inv[c];
#pragma unroll
                for (int rr = 0; rr < 4; ++rr) {
                    int r = wv * 16 + kg * 4 + rr;
                    float d = xnf[r] + cnc - 2.f * acc[nf][rr];
                    rbf[(size_t)(b0 + r) * NC + c] = f2bf(__expf(-d * ivc));
                }
            }
        }
    } else if (bid < 128) {
        // =================== csum reduce: 64 blocks x 512 pairs =============
        int p = (bid - 64) * 512 + t;
        float a0 = 0.f, a1 = 0.f, a2 = 0.f, a3 = 0.f;
#pragma unroll
        for (int r = 0; r < RCH; r += 4) {
            a0 += part[(size_t)(r + 0) * PAIRS + p];
            a1 += part[(size_t)(r + 1) * PAIRS + p];
            a2 += part[(size_t)(r + 2) * PAIRS + p];
            a3 += part[(size_t)(r + 3) * PAIRS + p];
        }
        int o = p >> 6, n = p & 63;
        wct[(size_t)o * KTOT + IN_F + n] = f2bf(((a0 + a1) + (a2 + a3)) * inv_S);
    } else if (bid < 192) {
        // =================== W^T -> wct cols 0..511 =========================
        float* tile = shbuf;               // 64 x 68
        int bb = bid - 128;
        int bi = bb >> 3, bj = bb & 7;
        int cq = t & 15, rq = t >> 4;      // rq 0..31
#pragma unroll
        for (int rr = 0; rr < 2; ++rr) {
            int row = rq * 2 + rr;
            float4 v = *(const float4*)(bw + (size_t)(bi * 64 + row) * OUT_F + bj * 64 + cq * 4);
            *(float4*)&tile[row * 68 + cq * 4] = v;
        }
        __syncthreads();
#pragma unroll
        for (int rr = 0; rr < 2; ++rr) {
            int orow = rq * 2 + rr;
            ushort4 w;
            w.x = f2bf(tile[(cq * 4 + 0) * 68 + orow]);
            w.y = f2bf(tile[(cq * 4 + 1) * 68 + orow]);
            w.z = f2bf(tile[(cq * 4 + 2) * 68 + orow]);
            w.w = f2bf(tile[(cq * 4 + 3) * 68 + orow]);
            *(ushort4*)(wct + (size_t)(bj * 64 + orow) * KTOT + bi * 64 + cq * 4) = w;
        }
    } else {
        // =================== kl final: 512 partials =========================
        float v = klpart[t];
        for (int off = 32; off; off >>= 1)
            v += __shfl_down(v, off, 64);
        float* wsum = shbuf;
        if ((t & 63) == 0) wsum[t >> 6] = v;
        __syncthreads();
        if (t == 0) {
            float s = 0.f;
#pragma unroll
            for (int i = 0; i < 8; ++i) s += wsum[i];
            kl_out[0] = 0.5f * s;
        }
    }
}

// ---------------------------------------------------------------------------
// K3: R1 structure + bijective XCD swizzle (512%8==0 -> bijective).
// Old mapping spread the 8 same-A-panel blocks across 8 XCDs (zero L2
// locality; A re-read x8, B x64 from L3). Swizzle gives each XCD 8 bm-panels
// x 8 bn: ~0.6MB A + 0.6MB B -> L2-resident.
// ---------------------------------------------------------------------------
__global__ __launch_bounds__(256)
void k3_mfma(const unsigned short* __restrict__ xbf,
             const unsigned short* __restrict__ rbf,
             const unsigned short* __restrict__ wct,
             float* __restrict__ out) {
    __shared__ __align__(16) unsigned short As[64 * 72];   // 9 KB
    __shared__ __align__(16) unsigned short Bs[64 * 72];   // 9 KB
    int t = threadIdx.x;
    int swz = (blockIdx.x & 7) * 64 + (blockIdx.x >> 3);   // XCD-chunked, bijective
    int bm = swz >> 3, bn = swz & 7;
    int b0 = bm * 64, o0 = bn * 64;
    int ar = t & 63, ah = t >> 6;        // staging: row, k-quarter(16)
    int lane = t & 63, wv = t >> 6;
    int fm = lane & 15, kg = lane >> 4;

    f32x4 acc[4] = {{0,0,0,0},{0,0,0,0},{0,0,0,0},{0,0,0,0}};
    const int abase = (wv * 16 + fm) * 72 + kg * 8;
    const int soff  = ar * 72 + ah * 16;

    for (int it = 0; it < 9; ++it) {
        bf16x8 av0, av1, bv0, bv1;
        if (it < 8) {
            int k0 = it * 64;
            av0 = *(const bf16x8*)(xbf + (size_t)(b0 + ar) * IN_F + k0 + ah * 16);
            av1 = *(const bf16x8*)(xbf + (size_t)(b0 + ar) * IN_F + k0 + ah * 16 + 8);
            bv0 = *(const bf16x8*)(wct + (size_t)(o0 + ar) * KTOT + k0 + ah * 16);
            bv1 = *(const bf16x8*)(wct + (size_t)(o0 + ar) * KTOT + k0 + ah * 16 + 8);
        } else {
            av0 = *(const bf16x8*)(rbf + (size_t)(b0 + ar) * NC + ah * 16);
            av1 = *(const bf16x8*)(rbf + (size_t)(b0 + ar) * NC + ah * 16 + 8);
            bv0 = *(const bf16x8*)(wct + (size_t)(o0 + ar) * KTOT + IN_F + ah * 16);
            bv1 = *(const bf16x8*)(wct + (size_t)(o0 + ar) * KTOT + IN_F + ah * 16 + 8);
        }
        __syncthreads();
        *(bf16x8*)&As[soff]     = av0;
        *(bf16x8*)&As[soff + 8] = av1;
        *(bf16x8*)&Bs[soff]     = bv0;
        *(bf16x8*)&Bs[soff + 8] = bv1;
        __syncthreads();
        bf16x8 af0 = *(bf16x8*)&As[abase];
        bf16x8 af1 = *(bf16x8*)&As[abase + 32];
#pragma unroll
        for (int nf = 0; nf < 4; ++nf) {
            bf16x8 b0f = *(bf16x8*)&Bs[(nf * 16 + fm) * 72 + kg * 8];
            acc[nf] = __builtin_amdgcn_mfma_f32_16x16x32_bf16(af0, b0f, acc[nf], 0, 0, 0);
            bf16x8 b1f = *(bf16x8*)&Bs[(nf * 16 + fm) * 72 + 32 + kg * 8];
            acc[nf] = __builtin_amdgcn_mfma_f32_16x16x32_bf16(af1, b1f, acc[nf], 0, 0, 0);
        }
    }

    // epilogue: C/D layout col=lane&15, row=(lane>>4)*4+reg
#pragma unroll
    for (int nf = 0; nf < 4; ++nf)
#pragma unroll
        for (int rr = 0; rr < 4; ++rr)
            out[(size_t)(b0 + wv * 16 + kg * 4 + rr) * OUT_F + o0 + nf * 16 + fm] = acc[nf][rr];
}

// ---------------------------------------------------------------------------
extern "C" void kernel_launch(void* const* d_in, const int* in_sizes, int n_in,
                              void* d_out, int out_size, void* d_ws, size_t ws_size,
                              hipStream_t stream) {
    const float* x         = (const float*)d_in[0];
    const float* centers   = (const float*)d_in[1];
    const float* log_sigma = (const float*)d_in[2];
    const float* cm        = (const float*)d_in[3];
    const float* clv       = (const float*)d_in[4];
    const float* bw        = (const float*)d_in[5];
    const float* eps       = (const float*)d_in[6];

    float* out = (float*)d_out;
    float* kl  = out + (size_t)B_SZ * OUT_F;

    // ws: [part 4MB][klpart 2KB][WcT 576KB bf16][rbf 512KB bf16][xbf 4MB bf16]
    float* part   = (float*)d_ws;
    float* klpart = part + (size_t)RCH * PAIRS;
    unsigned short* wct = (unsigned short*)(klpart + 512);
    unsigned short* rbf = wct + (size_t)OUT_F * KTOT;
    unsigned short* xbf = rbf + (size_t)B_SZ * NC;

    int S = in_sizes[6] / TOT;   // = 1

    k1_partial<<<512, 512, 0, stream>>>(cm, clv, eps, part, klpart, S);
    k_mid3<<<193, 512, 0, stream>>>(x, centers, log_sigma, part, klpart, bw,
                                    rbf, wct, xbf, kl, 1.0f / (float)S);
    k3_mfma<<<(B_SZ / 64) * (OUT_F / 64), 256, 0, stream>>>(xbf, rbf, wct, out);
}

// Round 12
// 221.611 us; speedup vs baseline: 1.1939x; 1.1939x over previous
//
#include <hip/hip_runtime.h>
#include <hip/hip_bf16.h>

#define B_SZ  4096
#define IN_F  512
#define OUT_F 512
#define NC    64
#define PAIRS 32768               // OUT_F * NC
#define TOT   (IN_F * PAIRS)      // 16.8M
#define KTOT  (IN_F + NC)         // 576: combined GEMM K
#define RCH   32                  // k1 row-chunks (16 rows each)

typedef __attribute__((ext_vector_type(8))) short bf16x8;
typedef __attribute__((ext_vector_type(4))) float f32x4;

static __device__ inline unsigned short f2bf(float f) {
    __hip_bfloat16 h = __float2bfloat16(f);   // RNE
    return *(unsigned short*)&h;
}

// ---------------------------------------------------------------------------
// K1: EXACT R8 config — nontemporal loads REQUIRED. R10 A/B proved it:
// plain loads = 96us @ 1.08 TB/s (L2-allocation thrash on a 192MB stream);
// nt loads = 42.5us @ 2.47 TB/s HBM + ~2 TB/s L3 (L2 bypass). FETCH is
// 98MB either way -> nt is an L2 streaming optimization, not L3 retention.
// DO NOT TOUCH.
// ---------------------------------------------------------------------------
__global__ __launch_bounds__(512)
void k1_partial(const float* __restrict__ cm,
                const float* __restrict__ clv,
                const float* __restrict__ eps,
                float* __restrict__ part,
                float* __restrict__ klpart,
                int S) {
    int pb = blockIdx.x & 15;            // pair-slice: 2048 pairs (8 KB/row)
    int rc = blockIdx.x >> 4;            // row-chunk: rows rc*16..+16
    int p4 = pb * 2048 + (threadIdx.x << 2);
    float Sf = (float)S;

    f32x4 s = {0.f, 0.f, 0.f, 0.f};
    float klp = 0.f;

    for (int g = 0; g < 2; ++g) {
        size_t base = (size_t)(rc * 16 + g * 8) * PAIRS + p4;
        f32x4 M[8], LV[8], ES[8];
#pragma unroll
        for (int ii = 0; ii < 8; ++ii)
            M[ii] = __builtin_nontemporal_load((const f32x4*)(cm + base + (size_t)ii * PAIRS));
#pragma unroll
        for (int ii = 0; ii < 8; ++ii)
            LV[ii] = __builtin_nontemporal_load((const f32x4*)(clv + base + (size_t)ii * PAIRS));
#pragma unroll
        for (int ii = 0; ii < 8; ++ii)
            ES[ii] = __builtin_nontemporal_load((const f32x4*)(eps + base + (size_t)ii * PAIRS));
        for (int si = 1; si < S; ++si)   // dead for S==1
#pragma unroll
            for (int ii = 0; ii < 8; ++ii) {
                f32x4 e = __builtin_nontemporal_load(
                    (const f32x4*)(eps + (size_t)si * TOT + base + (size_t)ii * PAIRS));
                ES[ii] += e;
            }

#pragma unroll
        for (int ii = 0; ii < 8; ++ii) {
            float e1x = __expf(0.5f * LV[ii].x);
            float e1y = __expf(0.5f * LV[ii].y);
            float e1z = __expf(0.5f * LV[ii].z);
            float e1w = __expf(0.5f * LV[ii].w);
            s.x += Sf * M[ii].x + ES[ii].x * e1x;
            s.y += Sf * M[ii].y + ES[ii].y * e1y;
            s.z += Sf * M[ii].z + ES[ii].z * e1z;
            s.w += Sf * M[ii].w + ES[ii].w * e1w;
            klp += (e1x*e1x + M[ii].x*M[ii].x - 1.f - LV[ii].x);
            klp += (e1y*e1y + M[ii].y*M[ii].y - 1.f - LV[ii].y);
            klp += (e1z*e1z + M[ii].z*M[ii].z - 1.f - LV[ii].z);
            klp += (e1w*e1w + M[ii].w*M[ii].w - 1.f - LV[ii].w);
        }
    }

    *(f32x4*)(part + (size_t)rc * PAIRS + p4) = s;

    for (int off = 32; off; off >>= 1)
        klp += __shfl_down(klp, off, 64);
    __shared__ float wsum[8];
    if ((threadIdx.x & 63) == 0) wsum[threadIdx.x >> 6] = klp;
    __syncthreads();
    if (threadIdx.x == 0) {
        float t = 0.f;
#pragma unroll
        for (int i = 0; i < 8; ++i) t += wsum[i];
        klpart[blockIdx.x] = t;
    }
}

// ---------------------------------------------------------------------------
// K_mid v3 (UNCHANGED from R8 — verified, part of the 225.8us config):
//   0..63   rbf via MFMA (dist^2 = ||x||^2 + ||c||^2 - 2 x.c) + xbf emit
//   64..127 csum reduce -> wct[*,512..575]
//   128..191 W^T -> wct cols 0..511
//   192     kl final
// ---------------------------------------------------------------------------
__global__ __launch_bounds__(512)
void k_mid3(const float* __restrict__ x,
            const float* __restrict__ centers,
            const float* __restrict__ log_sigma,
            const float* __restrict__ part,
            const float* __restrict__ klpart,
            const float* __restrict__ bw,
            unsigned short* __restrict__ rbf,
            unsigned short* __restrict__ wct,
            unsigned short* __restrict__ xbf,
            float* __restrict__ kl_out,
            float inv_S) {
    __shared__ __align__(16) float shbuf[5312];   // 21.25 KB, aliased per role
    int bid = blockIdx.x, t = threadIdx.x;

    if (bid < 64) {
        // =================== rbf-MFMA: rows b0..b0+63, all 64 centers ========
        unsigned short* As = (unsigned short*)shbuf;           // [64][72] bf16
        unsigned short* Cs = (unsigned short*)(shbuf + 2304);  // [64][72] bf16
        float* scr = shbuf + 4608;   // [512] partial scratch (cn, then xn)
        float* cn  = shbuf + 5120;   // [64] ||c||^2
        float* inv = shbuf + 5184;   // [64] 1/(2 sg^2 + 1e-8)
        float* xnf = shbuf + 5248;   // [64] ||x||^2

        int b0 = bid * 64;

        // ---- center norms + inv (f32 exact) ----
        {
            int n = t & 63, p = t >> 6;
            const float* cp = centers + (size_t)n * IN_F + p * 64;
            float s0 = 0.f, s1 = 0.f, s2 = 0.f, s3 = 0.f;
#pragma unroll
            for (int j = 0; j < 64; j += 4) {
                float4 v = *(const float4*)(cp + j);
                s0 = fmaf(v.x, v.x, s0); s1 = fmaf(v.y, v.y, s1);
                s2 = fmaf(v.z, v.z, s2); s3 = fmaf(v.w, v.w, s3);
            }
            scr[p * 64 + n] = (s0 + s1) + (s2 + s3);
        }
        __syncthreads();
        if (t < 64) {
            float s = 0.f;
#pragma unroll
            for (int p = 0; p < 8; ++p) s += scr[p * 64 + t];
            cn[t] = s;
            float sg = __expf(log_sigma[t]);
            inv[t] = 1.f / (2.f * sg * sg + 1e-8f);
        }
        __syncthreads();

        // ---- main loop: stage x/c tiles (f32->bf16), MFMA xc, emit xbf ----
        int ar = t >> 3, ah = t & 7;             // staging: row, k-octant(8)
        int lane = t & 63, wv = t >> 6;          // wv 0..7; MFMA on wv<4
        int fm = lane & 15, kg = lane >> 4;
        float xacc = 0.f;
        f32x4 acc[4] = {{0,0,0,0},{0,0,0,0},{0,0,0,0},{0,0,0,0}};

        for (int it = 0; it < 8; ++it) {
            int k0 = it * 64;
            const float* xp = x + (size_t)(b0 + ar) * IN_F + k0 + ah * 8;
            f32x4 v0 = *(const f32x4*)(xp);
            f32x4 v1 = *(const f32x4*)(xp + 4);
            const float* cp = centers + (size_t)ar * IN_F + k0 + ah * 8;
            f32x4 c0 = *(const f32x4*)(cp);
            f32x4 c1 = *(const f32x4*)(cp + 4);
            bf16x8 xb, cb;
            xb[0] = (short)f2bf(v0.x); xb[1] = (short)f2bf(v0.y);
            xb[2] = (short)f2bf(v0.z); xb[3] = (short)f2bf(v0.w);
            xb[4] = (short)f2bf(v1.x); xb[5] = (short)f2bf(v1.y);
            xb[6] = (short)f2bf(v1.z); xb[7] = (short)f2bf(v1.w);
            cb[0] = (short)f2bf(c0.x); cb[1] = (short)f2bf(c0.y);
            cb[2] = (short)f2bf(c0.z); cb[3] = (short)f2bf(c0.w);
            cb[4] = (short)f2bf(c1.x); cb[5] = (short)f2bf(c1.y);
            cb[6] = (short)f2bf(c1.z); cb[7] = (short)f2bf(c1.w);
            xacc += v0.x*v0.x + v0.y*v0.y + v0.z*v0.z + v0.w*v0.w
                  + v1.x*v1.x + v1.y*v1.y + v1.z*v1.z + v1.w*v1.w;
            __syncthreads();                       // prev MFMA done reading LDS
            *(bf16x8*)&As[ar * 72 + ah * 8] = xb;
            *(bf16x8*)&Cs[ar * 72 + ah * 8] = cb;
            *(bf16x8*)(xbf + (size_t)(b0 + ar) * IN_F + k0 + ah * 8) = xb;
            __syncthreads();
            if (wv < 4) {
                bf16x8 af0 = *(bf16x8*)&As[(wv * 16 + fm) * 72 + kg * 8];
                bf16x8 af1 = *(bf16x8*)&As[(wv * 16 + fm) * 72 + 32 + kg * 8];
#pragma unroll
                for (int nf = 0; nf < 4; ++nf) {
                    bf16x8 b0f = *(bf16x8*)&Cs[(nf * 16 + fm) * 72 + kg * 8];
                    acc[nf] = __builtin_amdgcn_mfma_f32_16x16x32_bf16(af0, b0f, acc[nf], 0, 0, 0);
                    bf16x8 b1f = *(bf16x8*)&Cs[(nf * 16 + fm) * 72 + 32 + kg * 8];
                    acc[nf] = __builtin_amdgcn_mfma_f32_16x16x32_bf16(af1, b1f, acc[nf], 0, 0, 0);
                }
            }
        }

        // ---- x row norms: reduce per-thread partials ----
        scr[ar * 8 + ah] = xacc;                   // scr last read pre-loop; safe
        __syncthreads();
        if (t < 64) {
            float s = 0.f;
#pragma unroll
            for (int p = 0; p < 8; ++p) s += scr[t * 8 + p];
            xnf[t] = s;
        }
        __syncthreads();

        // ---- epilogue: rbf = exp(-(xn + cn - 2 xc) * inv), C/D layout ----
        if (wv < 4) {
#pragma unroll
            for (int nf = 0; nf < 4; ++nf) {
                int c = nf * 16 + fm;
                float cnc = cn[c], ivc = inv[c];
#pragma unroll
                for (int rr = 0; rr < 4; ++rr) {
                    int r = wv * 16 + kg * 4 + rr;
                    float d = xnf[r] + cnc - 2.f * acc[nf][rr];
                    rbf[(size_t)(b0 + r) * NC + c] = f2bf(__expf(-d * ivc));
                }
            }
        }
    } else if (bid < 128) {
        // =================== csum reduce: 64 blocks x 512 pairs =============
        int p = (bid - 64) * 512 + t;
        float a0 = 0.f, a1 = 0.f, a2 = 0.f, a3 = 0.f;
#pragma unroll
        for (int r = 0; r < RCH; r += 4) {
            a0 += part[(size_t)(r + 0) * PAIRS + p];
            a1 += part[(size_t)(r + 1) * PAIRS + p];
            a2 += part[(size_t)(r + 2) * PAIRS + p];
            a3 += part[(size_t)(r + 3) * PAIRS + p];
        }
        int o = p >> 6, n = p & 63;
        wct[(size_t)o * KTOT + IN_F + n] = f2bf(((a0 + a1) + (a2 + a3)) * inv_S);
    } else if (bid < 192) {
        // =================== W^T -> wct cols 0..511 =========================
        float* tile = shbuf;               // 64 x 68
        int bb = bid - 128;
        int bi = bb >> 3, bj = bb & 7;
        int cq = t & 15, rq = t >> 4;      // rq 0..31
#pragma unroll
        for (int rr = 0; rr < 2; ++rr) {
            int row = rq * 2 + rr;
            float4 v = *(const float4*)(bw + (size_t)(bi * 64 + row) * OUT_F + bj * 64 + cq * 4);
            *(float4*)&tile[row * 68 + cq * 4] = v;
        }
        __syncthreads();
#pragma unroll
        for (int rr = 0; rr < 2; ++rr) {
            int orow = rq * 2 + rr;
            ushort4 w;
            w.x = f2bf(tile[(cq * 4 + 0) * 68 + orow]);
            w.y = f2bf(tile[(cq * 4 + 1) * 68 + orow]);
            w.z = f2bf(tile[(cq * 4 + 2) * 68 + orow]);
            w.w = f2bf(tile[(cq * 4 + 3) * 68 + orow]);
            *(ushort4*)(wct + (size_t)(bj * 64 + orow) * KTOT + bi * 64 + cq * 4) = w;
        }
    } else {
        // =================== kl final: 512 partials =========================
        float v = klpart[t];
        for (int off = 32; off; off >>= 1)
            v += __shfl_down(v, off, 64);
        float* wsum = shbuf;
        if ((t & 63) == 0) wsum[t >> 6] = v;
        __syncthreads();
        if (t == 0) {
            float s = 0.f;
#pragma unroll
            for (int i = 0; i < 8; ++i) s += wsum[i];
            kl_out[0] = 0.5f * s;
        }
    }
}

// ---------------------------------------------------------------------------
// K3: R1 structure + bijective XCD swizzle (kept from R10 — wall arithmetic
// suggests it contributed ~-14us while k1 regressed; this run prices it
// cleanly with k1 restored).
// ---------------------------------------------------------------------------
__global__ __launch_bounds__(256)
void k3_mfma(const unsigned short* __restrict__ xbf,
             const unsigned short* __restrict__ rbf,
             const unsigned short* __restrict__ wct,
             float* __restrict__ out) {
    __shared__ __align__(16) unsigned short As[64 * 72];   // 9 KB
    __shared__ __align__(16) unsigned short Bs[64 * 72];   // 9 KB
    int t = threadIdx.x;
    int swz = (blockIdx.x & 7) * 64 + (blockIdx.x >> 3);   // XCD-chunked, bijective
    int bm = swz >> 3, bn = swz & 7;
    int b0 = bm * 64, o0 = bn * 64;
    int ar = t & 63, ah = t >> 6;        // staging: row, k-quarter(16)
    int lane = t & 63, wv = t >> 6;
    int fm = lane & 15, kg = lane >> 4;

    f32x4 acc[4] = {{0,0,0,0},{0,0,0,0},{0,0,0,0},{0,0,0,0}};
    const int abase = (wv * 16 + fm) * 72 + kg * 8;
    const int soff  = ar * 72 + ah * 16;

    for (int it = 0; it < 9; ++it) {
        bf16x8 av0, av1, bv0, bv1;
        if (it < 8) {
            int k0 = it * 64;
            av0 = *(const bf16x8*)(xbf + (size_t)(b0 + ar) * IN_F + k0 + ah * 16);
            av1 = *(const bf16x8*)(xbf + (size_t)(b0 + ar) * IN_F + k0 + ah * 16 + 8);
            bv0 = *(const bf16x8*)(wct + (size_t)(o0 + ar) * KTOT + k0 + ah * 16);
            bv1 = *(const bf16x8*)(wct + (size_t)(o0 + ar) * KTOT + k0 + ah * 16 + 8);
        } else {
            av0 = *(const bf16x8*)(rbf + (size_t)(b0 + ar) * NC + ah * 16);
            av1 = *(const bf16x8*)(rbf + (size_t)(b0 + ar) * NC + ah * 16 + 8);
            bv0 = *(const bf16x8*)(wct + (size_t)(o0 + ar) * KTOT + IN_F + ah * 16);
            bv1 = *(const bf16x8*)(wct + (size_t)(o0 + ar) * KTOT + IN_F + ah * 16 + 8);
        }
        __syncthreads();
        *(bf16x8*)&As[soff]     = av0;
        *(bf16x8*)&As[soff + 8] = av1;
        *(bf16x8*)&Bs[soff]     = bv0;
        *(bf16x8*)&Bs[soff + 8] = bv1;
        __syncthreads();
        bf16x8 af0 = *(bf16x8*)&As[abase];
        bf16x8 af1 = *(bf16x8*)&As[abase + 32];
#pragma unroll
        for (int nf = 0; nf < 4; ++nf) {
            bf16x8 b0f = *(bf16x8*)&Bs[(nf * 16 + fm) * 72 + kg * 8];
            acc[nf] = __builtin_amdgcn_mfma_f32_16x16x32_bf16(af0, b0f, acc[nf], 0, 0, 0);
            bf16x8 b1f = *(bf16x8*)&Bs[(nf * 16 + fm) * 72 + 32 + kg * 8];
            acc[nf] = __builtin_amdgcn_mfma_f32_16x16x32_bf16(af1, b1f, acc[nf], 0, 0, 0);
        }
    }

    // epilogue: C/D layout col=lane&15, row=(lane>>4)*4+reg
#pragma unroll
    for (int nf = 0; nf < 4; ++nf)
#pragma unroll
        for (int rr = 0; rr < 4; ++rr)
            out[(size_t)(b0 + wv * 16 + kg * 4 + rr) * OUT_F + o0 + nf * 16 + fm] = acc[nf][rr];
}

// ---------------------------------------------------------------------------
extern "C" void kernel_launch(void* const* d_in, const int* in_sizes, int n_in,
                              void* d_out, int out_size, void* d_ws, size_t ws_size,
                              hipStream_t stream) {
    const float* x         = (const float*)d_in[0];
    const float* centers   = (const float*)d_in[1];
    const float* log_sigma = (const float*)d_in[2];
    const float* cm        = (const float*)d_in[3];
    const float* clv       = (const float*)d_in[4];
    const float* bw        = (const float*)d_in[5];
    const float* eps       = (const float*)d_in[6];

    float* out = (float*)d_out;
    float* kl  = out + (size_t)B_SZ * OUT_F;

    // ws: [part 4MB][klpart 2KB][WcT 576KB bf16][rbf 512KB bf16][xbf 4MB bf16]
    float* part   = (float*)d_ws;
    float* klpart = part + (size_t)RCH * PAIRS;
    unsigned short* wct = (unsigned short*)(klpart + 512);
    unsigned short* rbf = wct + (size_t)OUT_F * KTOT;
    unsigned short* xbf = rbf + (size_t)B_SZ * NC;

    int S = in_sizes[6] / TOT;   // = 1

    k1_partial<<<512, 512, 0, stream>>>(cm, clv, eps, part, klpart, S);
    k_mid3<<<193, 512, 0, stream>>>(x, centers, log_sigma, part, klpart, bw,
                                    rbf, wct, xbf, kl, 1.0f / (float)S);
    k3_mfma<<<(B_SZ / 64) * (OUT_F / 64), 256, 0, stream>>>(xbf, rbf, wct, out);
}